// Round 5
// baseline (2406.834 us; speedup 1.0000x reference)
//
#include <hip/hip_runtime.h>
#include <math.h>

#define CDIM 256
#define LSEQ 4096
#define NBH 16
#define NPTS 65536
#define KC 256

__device__ __forceinline__ float fadd(float a, float b){ return __fadd_rn(a,b); }
__device__ __forceinline__ float fmul(float a, float b){ return __fmul_rn(a,b); }
__device__ __forceinline__ float fsub(float a, float b){ return __fsub_rn(a,b); }

// numpy contiguous n=32 float32 sum, AVX-512 npyv path:
// vsum lane_j = e_j + e_{j+16}; then _mm512_reduce_add_ps halving tree:
// T3_j = lane_j + lane_{j+8}; T6_j = T3_j + T3_{j+4};
// result = (T6_0 + T6_2) + (T6_1 + T6_3)
__device__ __forceinline__ float sum32_np(const float* e){
    float l[16];
    #pragma unroll
    for (int j = 0; j < 16; j++) l[j] = fadd(e[j], e[j + 16]);
    float t3[8];
    #pragma unroll
    for (int j = 0; j < 8; j++) t3[j] = fadd(l[j], l[j + 8]);
    float t6[4];
    #pragma unroll
    for (int j = 0; j < 4; j++) t6[j] = fadd(t3[j], t3[j + 4]);
    return fadd(fadd(t6[0], t6[2]), fadd(t6[1], t6[3]));
}

// ---------- LayerNorm, numpy semantics (sequential over c) ----------
__global__ __launch_bounds__(256) void ln_np(const float* __restrict__ x,
        const float* __restrict__ g, const float* __restrict__ bt,
        float* __restrict__ y) {
    int gid = blockIdx.x * 256 + threadIdx.x;
    int b = gid >> 12, l = gid & 4095;
    const float* xb = x + (size_t)b * CDIM * LSEQ + l;
    float s = 0.f;
    for (int c = 0; c < 256; c++) s = fadd(s, xb[(size_t)c * LSEQ]);
    float mean = __fdiv_rn(s, 256.f);
    float s2 = 0.f;
    for (int c = 0; c < 256; c++) {
        float d = fsub(xb[(size_t)c * LSEQ], mean);
        s2 = fadd(s2, fmul(d, d));
    }
    float var = __fdiv_rn(s2, 256.f);
    float den = fadd(__fsqrt_rn(var), 1e-6f);
    float* yb = y + (size_t)b * CDIM * LSEQ + l;
    for (int c = 0; c < 256; c++) {
        float d = fsub(xb[(size_t)c * LSEQ], mean);
        yb[(size_t)c * LSEQ] = fadd(__fdiv_rn(fmul(g[c], d), den), bt[c]);
    }
}

// ---------- conv1x1, numpy einsum SOP semantics (no FMA, c ascending)
__global__ __launch_bounds__(256) void conv_np(const float* __restrict__ W, int wrow0,
        const float* __restrict__ X, float* __restrict__ Y, int nrows) {
    __shared__ float ws[64 * 256];
    int tid = threadIdx.x;
    int l = blockIdx.x * 256 + tid;
    int o0 = blockIdx.y * 64;
    int b = blockIdx.z;
    const float* wbase = W + (size_t)(wrow0 + o0) * CDIM;
    for (int i = tid; i < 64 * 256; i += 256) ws[i] = wbase[i];
    __syncthreads();
    const float* xb = X + (size_t)b * CDIM * LSEQ + l;
    float acc[64];
    #pragma unroll
    for (int i = 0; i < 64; i++) acc[i] = 0.f;
    for (int c = 0; c < 256; c++) {
        float xv = xb[(size_t)c * LSEQ];
        #pragma unroll
        for (int oo = 0; oo < 64; oo++)
            acc[oo] = fadd(acc[oo], fmul(ws[oo * 256 + c], xv));
    }
    for (int oo = 0; oo < 64; oo++)
        Y[((size_t)b * nrows + o0 + oo) * LSEQ + l] = acc[oo];
}

// ---------- fold (+ optional l2norm: strided axis -> sequential) ----
__global__ __launch_bounds__(256) void fold_np(const float* __restrict__ src,
        int srcRows, int row0, int donorm, float* __restrict__ dst) {
    int p = blockIdx.x * 256 + threadIdx.x;
    int bh = p >> 12, l = p & 4095;
    int b = bh >> 3, h = bh & 7;
    const float* sp = src + ((size_t)b * srcRows + row0 + h * 32) * LSEQ + l;
    float x[32];
    #pragma unroll
    for (int t = 0; t < 32; t++) x[t] = sp[(size_t)t * LSEQ];
    float* dp = dst + (size_t)p * 32;
    if (donorm) {
        float ss = 0.f;
        #pragma unroll
        for (int t = 0; t < 32; t++) ss = fadd(ss, fmul(x[t], x[t]));
        float n = __fsqrt_rn(ss);
        float den = fmaxf(n, 1e-12f);
        #pragma unroll
        for (int t = 0; t < 32; t++) dp[t] = __fdiv_rn(x[t], den);
    } else {
        #pragma unroll
        for (int t = 0; t < 32; t++) dp[t] = x[t];
    }
}

__global__ void copy32(const float* __restrict__ s, float* __restrict__ d, int n) {
    int i = blockIdx.x * 256 + threadIdx.x;
    if (i < n) d[i] = s[i];
}

// ---------- ||x||^2 per point (numpy AVX-512 tree over contig 32) ---
__global__ __launch_bounds__(256) void xx_np(const float* __restrict__ pts,
        float* __restrict__ xx) {
    int p = blockIdx.x * 256 + threadIdx.x;
    const float* x = pts + (size_t)p * 32;
    float e[32];
    #pragma unroll
    for (int t = 0; t < 32; t++) e[t] = fmul(x[t], x[t]);
    xx[p] = sum32_np(e);
}

// ---------- ||c||^2 per centroid ------------------------------------
__global__ __launch_bounds__(256) void cc_np(const float* __restrict__ cent,
        float* __restrict__ cc) {
    int j = threadIdx.x;
    const float* c = cent + (size_t)j * 32;
    float e[32];
    #pragma unroll
    for (int t = 0; t < 32; t++) e[t] = fmul(c[t], c[t]);
    cc[j] = sum32_np(e);
}

// ---------- argmin of expanded dist (sgemm-style fma dot) -----------
__global__ __launch_bounds__(256) void assign_np(const float* __restrict__ pts,
        const float* __restrict__ xx, const float* __restrict__ cent,
        const float* __restrict__ cc, int* __restrict__ asn) {
    __shared__ float sc[8192];
    __shared__ float scc[256];
    int tid = threadIdx.x;
    for (int i = tid; i < 8192; i += 256) sc[i] = cent[i];
    scc[tid] = cc[tid];
    __syncthreads();
    int p = blockIdx.x * 256 + tid;
    const float* pp = pts + (size_t)p * 32;
    float x[32];
    #pragma unroll
    for (int t = 0; t < 32; t++) x[t] = pp[t];
    float xp = xx[p];
    float bd = 3.4e38f; int bj = 0;
    for (int j = 0; j < 256; j++) {
        const float* cj = &sc[j * 32];
        float g = 0.f;
        #pragma unroll
        for (int t = 0; t < 32; t++) g = __builtin_fmaf(x[t], cj[t], g);
        float d = fadd(fsub(xp, fmul(2.f, g)), scc[j]);
        if (d < bd) { bd = d; bj = j; }
    }
    asn[p] = bj;
}

// ---------- stable counting sort (np.add.at order) ------------------
__global__ __launch_bounds__(256) void hist_np(const int* __restrict__ asn,
        int* __restrict__ hist) {
    __shared__ int bins[256];
    int tid = threadIdx.x, c = blockIdx.x;
    bins[tid] = 0;
    __syncthreads();
    int a = asn[c * 256 + tid];
    atomicAdd(&bins[a], 1);
    __syncthreads();
    hist[c * 256 + tid] = bins[tid];
}

__global__ __launch_bounds__(256) void scan_np(const int* __restrict__ hist,
        int* __restrict__ chunkbase, int* __restrict__ cbase, int* __restrict__ cnts) {
    __shared__ int tot[256];
    int j = threadIdx.x;
    int run = 0;
    for (int c = 0; c < 256; c++) {
        chunkbase[c * 256 + j] = run;
        run += hist[c * 256 + j];
    }
    tot[j] = run; cnts[j] = run;
    __syncthreads();
    if (j == 0) {
        int acc = 0;
        for (int q = 0; q < 256; q++) { cbase[q] = acc; acc += tot[q]; }
    }
}

__global__ __launch_bounds__(256) void scatter_np(const int* __restrict__ asn,
        const int* __restrict__ chunkbase, const int* __restrict__ cbase,
        int* __restrict__ perm) {
    __shared__ int lc[256];
    int tid = threadIdx.x, c = blockIdx.x;
    lc[tid] = 0;
    __syncthreads();
    if (tid == 0) {
        for (int i = 0; i < 256; i++) {
            int p = c * 256 + i;
            int a = asn[p];
            int r = lc[a]++;
            perm[cbase[a] + chunkbase[c * 256 + a] + r] = p;
        }
    }
}

// ---------- ordered per-cluster sums (exact add.at order) -----------
__global__ __launch_bounds__(256) void sumk_np(const float* __restrict__ pts,
        const int* __restrict__ perm, const int* __restrict__ cbase,
        const int* __restrict__ cnts, float* __restrict__ sums) {
    int gid = blockIdx.x * 256 + threadIdx.x;  // 8192
    int j = gid >> 5, t = gid & 31;
    int base = cbase[j], n = cnts[j];
    float s = 0.f;
    for (int i = 0; i < n; i++) {
        int p = perm[base + i];
        s = fadd(s, pts[(size_t)p * 32 + t]);
    }
    sums[j * 32 + t] = s;
}

__global__ __launch_bounds__(256) void update_np(float* __restrict__ cent,
        const float* __restrict__ sums, const int* __restrict__ cnts) {
    int i = blockIdx.x * 256 + threadIdx.x;  // 8192
    int j = i >> 5;
    int c = cnts[j];
    if (c > 0) cent[i] = __fdiv_rn(sums[i], (float)c);
}

// ---------- key assign + L1 dist (AVX-512 tree over contig 32) ------
__global__ __launch_bounds__(256) void kdist_np(const float* __restrict__ pts,
        const float* __restrict__ xx, const float* __restrict__ cent,
        const float* __restrict__ cc, float* __restrict__ kd) {
    __shared__ float sc[8192];
    __shared__ float scc[256];
    int tid = threadIdx.x;
    for (int i = tid; i < 8192; i += 256) sc[i] = cent[i];
    scc[tid] = cc[tid];
    __syncthreads();
    int p = blockIdx.x * 256 + tid;
    const float* pp = pts + (size_t)p * 32;
    float x[32];
    #pragma unroll
    for (int t = 0; t < 32; t++) x[t] = pp[t];
    float xp = xx[p];
    float bd = 3.4e38f; int bj = 0;
    for (int j = 0; j < 256; j++) {
        const float* cj = &sc[j * 32];
        float g = 0.f;
        #pragma unroll
        for (int t = 0; t < 32; t++) g = __builtin_fmaf(x[t], cj[t], g);
        float d = fadd(fsub(xp, fmul(2.f, g)), scc[j]);
        if (d < bd) { bd = d; bj = j; }
    }
    const float* cb = &sc[bj * 32];
    float e[32];
    #pragma unroll
    for (int t = 0; t < 32; t++) e[t] = fabsf(fsub(cb[t], x[t]));
    kd[p] = sum32_np(e);
}

// ---------- top-256 (desc, idx-asc ties) + gather -------------------
__global__ __launch_bounds__(512) void topk_gather(const float* __restrict__ kd,
        const float* __restrict__ k_t, const float* __restrict__ v_t,
        float* __restrict__ ksel, float* __restrict__ vsel) {
    __shared__ float vals[4096];
    __shared__ int   idxs[4096];
    int bh = blockIdx.x, tid = threadIdx.x;
    for (int i = tid; i < 4096; i += 512) { vals[i] = kd[bh * 4096 + i]; idxs[i] = i; }
    __syncthreads();
    for (int k = 2; k <= 4096; k <<= 1) {
        for (int j = k >> 1; j > 0; j >>= 1) {
            for (int i = tid; i < 4096; i += 512) {
                int ixj = i ^ j;
                if (ixj > i) {
                    bool up = ((i & k) == 0);
                    float vi = vals[i], vx = vals[ixj];
                    int ii = idxs[i], ix = idxs[ixj];
                    bool before = (vi > vx) || (vi == vx && ii < ix);
                    bool sw = up ? !before : before;
                    if (sw) { vals[i] = vx; vals[ixj] = vi; idxs[i] = ix; idxs[ixj] = ii; }
                }
            }
            __syncthreads();
        }
    }
    for (int e = tid; e < 256 * 32; e += 512) {
        int jj = e >> 5, t = e & 31;
        int src = idxs[jj];
        ksel[(size_t)bh * 8192 + e] = k_t[((size_t)bh * 4096 + src) * 32 + t];
        vsel[(size_t)bh * 8192 + e] = v_t[((size_t)bh * 4096 + src) * 32 + t];
    }
}

// ---------- attention (online softmax), fp32 value path -------------
__global__ __launch_bounds__(256) void attn_kernel(const float* __restrict__ q_t,
        const float* __restrict__ ksel, const float* __restrict__ vsel,
        float* __restrict__ out) {
    __shared__ float sk[8192];
    __shared__ float sv[8192];
    int bh = blockIdx.y, tid = threadIdx.x;
    {
        const float4* gk = (const float4*)(ksel + (size_t)bh * 8192);
        const float4* gv = (const float4*)(vsel + (size_t)bh * 8192);
        float4* k4s = (float4*)sk; float4* v4s = (float4*)sv;
        for (int i = tid; i < 2048; i += 256) { k4s[i] = gk[i]; v4s[i] = gv[i]; }
    }
    __syncthreads();
    int p = bh * 4096 + blockIdx.x * 256 + tid;
    float q[32];
    const float4* qp = (const float4*)(q_t + (size_t)p * 32);
    #pragma unroll
    for (int t = 0; t < 8; t++) {
        float4 f = qp[t];
        q[4*t] = f.x; q[4*t+1] = f.y; q[4*t+2] = f.z; q[4*t+3] = f.w;
    }
    float o[32];
    #pragma unroll
    for (int t = 0; t < 32; t++) o[t] = 0.f;
    float m = -3.0e38f, lsum = 0.f;
    const float4* k4 = (const float4*)sk;
    const float4* v4 = (const float4*)sv;
    for (int j = 0; j < 256; j++) {
        float s = 0.f;
        #pragma unroll
        for (int t = 0; t < 8; t++) {
            float4 kf = k4[j * 8 + t];
            s += q[4*t]*kf.x + q[4*t+1]*kf.y + q[4*t+2]*kf.z + q[4*t+3]*kf.w;
        }
        float mn = fmaxf(m, s);
        float alpha = expf(m - mn);
        float w = expf(s - mn);
        lsum = lsum * alpha + w;
        #pragma unroll
        for (int t = 0; t < 8; t++) {
            float4 vf = v4[j * 8 + t];
            o[4*t]   = o[4*t]   * alpha + w * vf.x;
            o[4*t+1] = o[4*t+1] * alpha + w * vf.y;
            o[4*t+2] = o[4*t+2] * alpha + w * vf.z;
            o[4*t+3] = o[4*t+3] * alpha + w * vf.w;
        }
        m = mn;
    }
    float inv = 1.f / lsum;
    float4* op = (float4*)(out + (size_t)p * 32);
    #pragma unroll
    for (int t = 0; t < 8; t++)
        op[t] = make_float4(o[4*t]*inv, o[4*t+1]*inv, o[4*t+2]*inv, o[4*t+3]*inv);
}

// ---------- unfold (bh,L,32) -> (b,256,L) ---------------------------
__global__ __launch_bounds__(256) void unfold_kernel(const float* __restrict__ att,
        float* __restrict__ Fo) {
    __shared__ float tbuf[32][65];
    int bh = blockIdx.y, l0 = blockIdx.x * 64;
    int b = bh >> 3, h = bh & 7;
    int tid = threadIdx.x;
    #pragma unroll
    for (int r = 0; r < 8; r++) {
        int e = r * 256 + tid;
        int l = e >> 5, d = e & 31;
        tbuf[d][l] = att[((size_t)bh * 4096 + l0 + l) * 32 + d];
    }
    __syncthreads();
    #pragma unroll
    for (int r = 0; r < 8; r++) {
        int e = r * 256 + tid;
        int d = e >> 6, l = e & 63;
        Fo[((size_t)b * 256 + h * 32 + d) * LSEQ + l0 + l] = tbuf[d][l];
    }
}

// ---------- final LN + scale + residual (numpy orders) --------------
__global__ __launch_bounds__(256) void lnres_np(const float* __restrict__ x,
        const float* __restrict__ g, const float* __restrict__ bt,
        const float* __restrict__ gs, const float* __restrict__ qsrc,
        float* __restrict__ y) {
    int gid = blockIdx.x * 256 + threadIdx.x;
    int b = gid >> 12, l = gid & 4095;
    const float* xb = x + (size_t)b * CDIM * LSEQ + l;
    float s = 0.f;
    for (int c = 0; c < 256; c++) s = fadd(s, xb[(size_t)c * LSEQ]);
    float mean = __fdiv_rn(s, 256.f);
    float s2 = 0.f;
    for (int c = 0; c < 256; c++) {
        float d = fsub(xb[(size_t)c * LSEQ], mean);
        s2 = fadd(s2, fmul(d, d));
    }
    float var = __fdiv_rn(s2, 256.f);
    float den = fadd(__fsqrt_rn(var), 1e-6f);
    float scale = gs[0];
    const float* qb = qsrc + (size_t)b * CDIM * LSEQ + l;
    float* yb = y + (size_t)b * CDIM * LSEQ + l;
    for (int c = 0; c < 256; c++) {
        float d = fsub(xb[(size_t)c * LSEQ], mean);
        float r = fadd(__fdiv_rn(fmul(g[c], d), den), bt[c]);
        yb[(size_t)c * LSEQ] = fadd(fmul(scale, r), qb[(size_t)c * LSEQ]);
    }
}

// ==================================================================
extern "C" void kernel_launch(void* const* d_in, const int* in_sizes, int n_in,
                              void* d_out, int out_size, void* d_ws, size_t ws_size,
                              hipStream_t stream) {
    const float* qsrc   = (const float*)d_in[0];
    const float* ctx    = (const float*)d_in[1];
    const float* w_q    = (const float*)d_in[2];
    const float* w_kv   = (const float*)d_in[3];
    const float* w_out  = (const float*)d_in[4];
    const float* g_ctx  = (const float*)d_in[5];
    const float* b_ctx  = (const float*)d_in[6];
    const float* g_q    = (const float*)d_in[7];
    const float* b_q    = (const float*)d_in[8];
    const float* g_out  = (const float*)d_in[9];
    const float* b_out  = (const float*)d_in[10];
    const float* gs     = (const float*)d_in[11];

    char* base = (char*)d_ws;
    const size_t MB = 1024 * 1024;
    float* yln   = (float*)base;               // [0,8) LN out; later att
    float* att   = (float*)base;
    float* kvbuf = (float*)(base + 8 * MB);    // [8,24) kv conv; later y32 [8,16)
    float* y32   = (float*)(base + 8 * MB);
    float* qbuf  = (float*)(base + 24 * MB);   // [24,32) q conv; later Fo
    float* Fo    = (float*)(base + 24 * MB);
    float* q_t   = (float*)(base + 32 * MB);   // [32,40)
    float* k_t   = (float*)(base + 40 * MB);   // [40,48)
    float* v_t   = (float*)(base + 48 * MB);   // [48,56)
    char* SM = base + 56 * MB;
    float* xx_q      = (float*)(SM + 0);            // 256 KB
    float* xx_k      = (float*)(SM + 256 * 1024);   // 256 KB
    float* cent      = (float*)(SM + 512 * 1024);   // 32 KB
    float* cc        = (float*)(SM + 576 * 1024);   // 1 KB
    float* sums      = (float*)(SM + 640 * 1024);   // 32 KB
    int*   cnts      = (int*)  (SM + 704 * 1024);   // 1 KB
    int*   asn       = (int*)  (SM + 768 * 1024);   // 256 KB
    int*   hist      = (int*)  (SM + 1024 * 1024);  // 256 KB
    int*   chunkbase = (int*)  (SM + 1280 * 1024);  // 256 KB
    int*   cbase     = (int*)  (SM + 1536 * 1024);  // 1 KB
    int*   perm      = (int*)  (SM + 1600 * 1024);  // 256 KB
    float* kd        = (float*)(SM + 1856 * 1024);  // 256 KB
    float* ksel      = (float*)(SM + 2112 * 1024);  // 512 KB
    float* vsel      = (float*)(SM + 2624 * 1024);  // 512 KB

    // context branch
    ln_np<<<32, 256, 0, stream>>>(ctx, g_ctx, b_ctx, yln);
    conv_np<<<dim3(16, 8, 2), 256, 0, stream>>>(w_kv, 0, yln, kvbuf, 512);
    fold_np<<<256, 256, 0, stream>>>(kvbuf, 512, 0, 1, k_t);
    fold_np<<<256, 256, 0, stream>>>(kvbuf, 512, 256, 0, v_t);
    // query branch
    ln_np<<<32, 256, 0, stream>>>(qsrc, g_q, b_q, yln);
    conv_np<<<dim3(16, 4, 2), 256, 0, stream>>>(w_q, 0, yln, qbuf, 256);
    fold_np<<<256, 256, 0, stream>>>(qbuf, 256, 0, 1, q_t);

    xx_np<<<256, 256, 0, stream>>>(q_t, xx_q);
    copy32<<<32, 256, 0, stream>>>(q_t, cent, 8192);

    for (int it = 0; it < 10; it++) {
        cc_np<<<1, 256, 0, stream>>>(cent, cc);
        assign_np<<<256, 256, 0, stream>>>(q_t, xx_q, cent, cc, asn);
        hist_np<<<256, 256, 0, stream>>>(asn, hist);
        scan_np<<<1, 256, 0, stream>>>(hist, chunkbase, cbase, cnts);
        scatter_np<<<256, 256, 0, stream>>>(asn, chunkbase, cbase, perm);
        sumk_np<<<32, 256, 0, stream>>>(q_t, perm, cbase, cnts, sums);
        update_np<<<32, 256, 0, stream>>>(cent, sums, cnts);
    }

    xx_np<<<256, 256, 0, stream>>>(k_t, xx_k);
    cc_np<<<1, 256, 0, stream>>>(cent, cc);
    kdist_np<<<256, 256, 0, stream>>>(k_t, xx_k, cent, cc, kd);
    topk_gather<<<16, 512, 0, stream>>>(kd, k_t, v_t, ksel, vsel);
    attn_kernel<<<dim3(16, 16), 256, 0, stream>>>(q_t, ksel, vsel, att);
    unfold_kernel<<<dim3(64, 16), 256, 0, stream>>>(att, Fo);
    conv_np<<<dim3(16, 4, 2), 256, 0, stream>>>(w_out, 0, Fo, y32, 256);
    lnres_np<<<32, 256, 0, stream>>>(y32, g_out, b_out, gs, qsrc, (float*)d_out);
}

// Round 6
// 2020.559 us; speedup vs baseline: 1.1912x; 1.1912x over previous
//
#include <hip/hip_runtime.h>
#include <math.h>

#define CDIM 256
#define LSEQ 4096
#define NBH 16
#define NPTS 65536
#define KC 256

__device__ __forceinline__ float fadd(float a, float b){ return __fadd_rn(a,b); }
__device__ __forceinline__ float fmul(float a, float b){ return __fmul_rn(a,b); }
__device__ __forceinline__ float fsub(float a, float b){ return __fsub_rn(a,b); }

// numpy contiguous n=32 float32 sum, AVX-512 npyv path (verified R5)
__device__ __forceinline__ float sum32_np(const float* e){
    float l[16];
    #pragma unroll
    for (int j = 0; j < 16; j++) l[j] = fadd(e[j], e[j + 16]);
    float t3[8];
    #pragma unroll
    for (int j = 0; j < 8; j++) t3[j] = fadd(l[j], l[j + 8]);
    float t6[4];
    #pragma unroll
    for (int j = 0; j < 4; j++) t6[j] = fadd(t3[j], t3[j + 4]);
    return fadd(fadd(t6[0], t6[2]), fadd(t6[1], t6[3]));
}

// ---------- LayerNorm, numpy semantics (sequential over c) ----------
// grid 128 x block 64 (128 CUs busy; loads are independent -> MLP)
__global__ __launch_bounds__(64) void ln_np(const float* __restrict__ x,
        const float* __restrict__ g, const float* __restrict__ bt,
        float* __restrict__ y) {
    int gid = blockIdx.x * 64 + threadIdx.x;
    int b = gid >> 12, l = gid & 4095;
    const float* xb = x + (size_t)b * CDIM * LSEQ + l;
    float s = 0.f;
    for (int c = 0; c < 256; c++) s = fadd(s, xb[(size_t)c * LSEQ]);
    float mean = __fdiv_rn(s, 256.f);
    float s2 = 0.f;
    for (int c = 0; c < 256; c++) {
        float d = fsub(xb[(size_t)c * LSEQ], mean);
        s2 = fadd(s2, fmul(d, d));
    }
    float var = __fdiv_rn(s2, 256.f);
    float den = fadd(__fsqrt_rn(var), 1e-6f);
    float* yb = y + (size_t)b * CDIM * LSEQ + l;
    for (int c = 0; c < 256; c++) {
        float d = fsub(xb[(size_t)c * LSEQ], mean);
        yb[(size_t)c * LSEQ] = fadd(__fdiv_rn(fmul(g[c], d), den), bt[c]);
    }
}

// ---------- conv1x1, numpy einsum SOP semantics (no FMA, c ascending)
__global__ __launch_bounds__(256) void conv_np(const float* __restrict__ W, int wrow0,
        const float* __restrict__ X, float* __restrict__ Y, int nrows) {
    __shared__ float ws[64 * 256];
    int tid = threadIdx.x;
    int l = blockIdx.x * 256 + tid;
    int o0 = blockIdx.y * 64;
    int b = blockIdx.z;
    const float* wbase = W + (size_t)(wrow0 + o0) * CDIM;
    for (int i = tid; i < 64 * 256; i += 256) ws[i] = wbase[i];
    __syncthreads();
    const float* xb = X + (size_t)b * CDIM * LSEQ + l;
    float acc[64];
    #pragma unroll
    for (int i = 0; i < 64; i++) acc[i] = 0.f;
    for (int c = 0; c < 256; c++) {
        float xv = xb[(size_t)c * LSEQ];
        #pragma unroll
        for (int oo = 0; oo < 64; oo++)
            acc[oo] = fadd(acc[oo], fmul(ws[oo * 256 + c], xv));
    }
    for (int oo = 0; oo < 64; oo++)
        Y[((size_t)b * nrows + o0 + oo) * LSEQ + l] = acc[oo];
}

// ---------- fold (+ optional l2norm: strided axis -> sequential) ----
__global__ __launch_bounds__(256) void fold_np(const float* __restrict__ src,
        int srcRows, int row0, int donorm, float* __restrict__ dst) {
    int p = blockIdx.x * 256 + threadIdx.x;
    int bh = p >> 12, l = p & 4095;
    int b = bh >> 3, h = bh & 7;
    const float* sp = src + ((size_t)b * srcRows + row0 + h * 32) * LSEQ + l;
    float x[32];
    #pragma unroll
    for (int t = 0; t < 32; t++) x[t] = sp[(size_t)t * LSEQ];
    float* dp = dst + (size_t)p * 32;
    if (donorm) {
        float ss = 0.f;
        #pragma unroll
        for (int t = 0; t < 32; t++) ss = fadd(ss, fmul(x[t], x[t]));
        float n = __fsqrt_rn(ss);
        float den = fmaxf(n, 1e-12f);
        #pragma unroll
        for (int t = 0; t < 32; t++) dp[t] = __fdiv_rn(x[t], den);
    } else {
        #pragma unroll
        for (int t = 0; t < 32; t++) dp[t] = x[t];
    }
}

__global__ void copy32(const float* __restrict__ s, float* __restrict__ d, int n) {
    int i = blockIdx.x * 256 + threadIdx.x;
    if (i < n) d[i] = s[i];
}

// ---------- ||x||^2 per point (AVX-512 tree) ------------------------
__global__ __launch_bounds__(256) void xx_np(const float* __restrict__ pts,
        float* __restrict__ xx) {
    int p = blockIdx.x * 256 + threadIdx.x;
    const float* x = pts + (size_t)p * 32;
    float e[32];
    #pragma unroll
    for (int t = 0; t < 32; t++) e[t] = fmul(x[t], x[t]);
    xx[p] = sum32_np(e);
}

// ---------- ||c||^2 per centroid (initial) --------------------------
__global__ __launch_bounds__(256) void cc_np(const float* __restrict__ cent,
        float* __restrict__ cc) {
    int j = threadIdx.x;
    const float* c = cent + (size_t)j * 32;
    float e[32];
    #pragma unroll
    for (int t = 0; t < 32; t++) e[t] = fmul(c[t], c[t]);
    cc[j] = sum32_np(e);
}

// ---------- argmin + block-local histogram (fused) ------------------
// centroids read from global: wave-uniform -> scalar loads, bits identical
__global__ __launch_bounds__(256) void assign_hist_np(const float* __restrict__ pts,
        const float* __restrict__ xx, const float* __restrict__ cent,
        const float* __restrict__ cc, int* __restrict__ asn, int* __restrict__ hist) {
    __shared__ int bins[256];
    int tid = threadIdx.x, c = blockIdx.x;
    bins[tid] = 0;
    __syncthreads();
    int p = c * 256 + tid;
    const float* pp = pts + (size_t)p * 32;
    float x[32];
    #pragma unroll
    for (int t = 0; t < 32; t++) x[t] = pp[t];
    float xp = xx[p];
    float bd = 3.4e38f; int bj = 0;
    for (int j = 0; j < 256; j++) {
        const float* cj = cent + (size_t)j * 32;
        float g = 0.f;
        #pragma unroll
        for (int t = 0; t < 32; t++) g = __builtin_fmaf(x[t], cj[t], g);
        float d = fadd(fsub(xp, fmul(2.f, g)), cc[j]);
        if (d < bd) { bd = d; bj = j; }
    }
    asn[p] = bj;
    atomicAdd(&bins[bj], 1);
    __syncthreads();
    hist[c * 256 + tid] = bins[tid];
}

// ---------- scan (exact integer) ------------------------------------
__global__ __launch_bounds__(256) void scan_np(const int* __restrict__ hist,
        int* __restrict__ chunkbase, int* __restrict__ cbase, int* __restrict__ cnts) {
    __shared__ int tot[256];
    int j = threadIdx.x;
    int run = 0;
    #pragma unroll 8
    for (int c = 0; c < 256; c++) {
        chunkbase[c * 256 + j] = run;
        run += hist[c * 256 + j];
    }
    tot[j] = run; cnts[j] = run;
    __syncthreads();
    if (j == 0) {
        int acc = 0;
        for (int q = 0; q < 256; q++) { cbase[q] = acc; acc += tot[q]; }
    }
}

// ---------- scatter with parallel stable rank -----------------------
// identical perm to serial version: chunk-ascending, tid-ascending
__global__ __launch_bounds__(256) void scatter_v2(const int* __restrict__ asn,
        const int* __restrict__ chunkbase, const int* __restrict__ cbase,
        int* __restrict__ perm) {
    __shared__ int a[256];
    int c = blockIdx.x, tid = threadIdx.x;
    a[tid] = asn[c * 256 + tid];
    __syncthreads();
    int my = a[tid];
    int r = 0;
    for (int i = 0; i < tid; i++) r += (a[i] == my) ? 1 : 0;
    perm[cbase[my] + chunkbase[c * 256 + my] + r] = c * 256 + tid;
}

// ---------- ordered per-cluster sums: LDS-pipelined, exact order ----
// one block per cluster; 256 threads gather 128-row tiles (double buffer);
// 32 lanes replay the exact sequential fp32 add order from LDS.
#define STILE 128
__global__ __launch_bounds__(256) void sumk_v2(const float* __restrict__ pts,
        const int* __restrict__ perm, const int* __restrict__ cbase,
        const int* __restrict__ cnts, float* __restrict__ sums) {
    __shared__ float buf[2][STILE][32];
    int j = blockIdx.x, tid = threadIdx.x;
    int base = cbase[j], n = cnts[j];
    int t = tid & 31, r0 = tid >> 5;
    // tile 0
    for (int r = r0; r < STILE; r += 8) {
        if (r < n) buf[0][r][t] = pts[(size_t)perm[base + r] * 32 + t];
    }
    __syncthreads();
    float s = 0.f;
    int b = 0;
    for (int i0 = 0; i0 < n; i0 += STILE, b ^= 1) {
        int nx = i0 + STILE;
        if (nx < n) {
            for (int r = r0; r < STILE; r += 8) {
                int g = nx + r;
                if (g < n) buf[b ^ 1][r][t] = pts[(size_t)perm[base + g] * 32 + t];
            }
        }
        if (tid < 32) {
            int m = n - i0; if (m > STILE) m = STILE;
            int i = 0;
            for (; i + 4 <= m; i += 4) {
                s = fadd(s, buf[b][i][tid]);
                s = fadd(s, buf[b][i + 1][tid]);
                s = fadd(s, buf[b][i + 2][tid]);
                s = fadd(s, buf[b][i + 3][tid]);
            }
            for (; i < m; i++) s = fadd(s, buf[b][i][tid]);
        }
        __syncthreads();
    }
    if (tid < 32) sums[j * 32 + tid] = s;
}

// ---------- update + cc via exact-order xor butterfly ---------------
// butterfly == sum32_np tree bitwise (fadd commutative; order verified)
__global__ __launch_bounds__(256) void update_cc_np(float* __restrict__ cent,
        const float* __restrict__ sums, const int* __restrict__ cnts,
        float* __restrict__ cc) {
    int i = blockIdx.x * 256 + threadIdx.x;  // 8192
    int j = i >> 5;
    int c = cnts[j];
    float v = cent[i];
    if (c > 0) { v = __fdiv_rn(sums[i], (float)c); cent[i] = v; }
    float e = fmul(v, v);
    e = fadd(e, __shfl_xor(e, 16));
    e = fadd(e, __shfl_xor(e, 8));
    e = fadd(e, __shfl_xor(e, 4));
    e = fadd(e, __shfl_xor(e, 2));
    e = fadd(e, __shfl_xor(e, 1));
    if ((i & 31) == 0) cc[j] = e;
}

// ---------- key assign + L1 dist (AVX-512 tree) ---------------------
__global__ __launch_bounds__(256) void kdist_np(const float* __restrict__ pts,
        const float* __restrict__ xx, const float* __restrict__ cent,
        const float* __restrict__ cc, float* __restrict__ kd) {
    int tid = threadIdx.x;
    int p = blockIdx.x * 256 + tid;
    const float* pp = pts + (size_t)p * 32;
    float x[32];
    #pragma unroll
    for (int t = 0; t < 32; t++) x[t] = pp[t];
    float xp = xx[p];
    float bd = 3.4e38f; int bj = 0;
    for (int j = 0; j < 256; j++) {
        const float* cj = cent + (size_t)j * 32;
        float g = 0.f;
        #pragma unroll
        for (int t = 0; t < 32; t++) g = __builtin_fmaf(x[t], cj[t], g);
        float d = fadd(fsub(xp, fmul(2.f, g)), cc[j]);
        if (d < bd) { bd = d; bj = j; }
    }
    const float* cb = cent + (size_t)bj * 32;
    float e[32];
    #pragma unroll
    for (int t = 0; t < 32; t++) e[t] = fabsf(fsub(cb[t], x[t]));
    kd[p] = sum32_np(e);
}

// ---------- top-256 (desc, idx-asc ties) + gather -------------------
__global__ __launch_bounds__(512) void topk_gather(const float* __restrict__ kd,
        const float* __restrict__ k_t, const float* __restrict__ v_t,
        float* __restrict__ ksel, float* __restrict__ vsel) {
    __shared__ float vals[4096];
    __shared__ int   idxs[4096];
    int bh = blockIdx.x, tid = threadIdx.x;
    for (int i = tid; i < 4096; i += 512) { vals[i] = kd[bh * 4096 + i]; idxs[i] = i; }
    __syncthreads();
    for (int k = 2; k <= 4096; k <<= 1) {
        for (int j = k >> 1; j > 0; j >>= 1) {
            for (int i = tid; i < 4096; i += 512) {
                int ixj = i ^ j;
                if (ixj > i) {
                    bool up = ((i & k) == 0);
                    float vi = vals[i], vx = vals[ixj];
                    int ii = idxs[i], ix = idxs[ixj];
                    bool before = (vi > vx) || (vi == vx && ii < ix);
                    bool sw = up ? !before : before;
                    if (sw) { vals[i] = vx; vals[ixj] = vi; idxs[i] = ix; idxs[ixj] = ii; }
                }
            }
            __syncthreads();
        }
    }
    for (int e = tid; e < 256 * 32; e += 512) {
        int jj = e >> 5, t = e & 31;
        int src = idxs[jj];
        ksel[(size_t)bh * 8192 + e] = k_t[((size_t)bh * 4096 + src) * 32 + t];
        vsel[(size_t)bh * 8192 + e] = v_t[((size_t)bh * 4096 + src) * 32 + t];
    }
}

// ---------- attention (online softmax), fp32 value path -------------
__global__ __launch_bounds__(256) void attn_kernel(const float* __restrict__ q_t,
        const float* __restrict__ ksel, const float* __restrict__ vsel,
        float* __restrict__ out) {
    __shared__ float sk[8192];
    __shared__ float sv[8192];
    int bh = blockIdx.y, tid = threadIdx.x;
    {
        const float4* gk = (const float4*)(ksel + (size_t)bh * 8192);
        const float4* gv = (const float4*)(vsel + (size_t)bh * 8192);
        float4* k4s = (float4*)sk; float4* v4s = (float4*)sv;
        for (int i = tid; i < 2048; i += 256) { k4s[i] = gk[i]; v4s[i] = gv[i]; }
    }
    __syncthreads();
    int p = bh * 4096 + blockIdx.x * 256 + tid;
    float q[32];
    const float4* qp = (const float4*)(q_t + (size_t)p * 32);
    #pragma unroll
    for (int t = 0; t < 8; t++) {
        float4 f = qp[t];
        q[4*t] = f.x; q[4*t+1] = f.y; q[4*t+2] = f.z; q[4*t+3] = f.w;
    }
    float o[32];
    #pragma unroll
    for (int t = 0; t < 32; t++) o[t] = 0.f;
    float m = -3.0e38f, lsum = 0.f;
    const float4* k4 = (const float4*)sk;
    const float4* v4 = (const float4*)sv;
    for (int j = 0; j < 256; j++) {
        float s = 0.f;
        #pragma unroll
        for (int t = 0; t < 8; t++) {
            float4 kf = k4[j * 8 + t];
            s += q[4*t]*kf.x + q[4*t+1]*kf.y + q[4*t+2]*kf.z + q[4*t+3]*kf.w;
        }
        float mn = fmaxf(m, s);
        float alpha = expf(m - mn);
        float w = expf(s - mn);
        lsum = lsum * alpha + w;
        #pragma unroll
        for (int t = 0; t < 8; t++) {
            float4 vf = v4[j * 8 + t];
            o[4*t]   = o[4*t]   * alpha + w * vf.x;
            o[4*t+1] = o[4*t+1] * alpha + w * vf.y;
            o[4*t+2] = o[4*t+2] * alpha + w * vf.z;
            o[4*t+3] = o[4*t+3] * alpha + w * vf.w;
        }
        m = mn;
    }
    float inv = 1.f / lsum;
    float4* op = (float4*)(out + (size_t)p * 32);
    #pragma unroll
    for (int t = 0; t < 8; t++)
        op[t] = make_float4(o[4*t]*inv, o[4*t+1]*inv, o[4*t+2]*inv, o[4*t+3]*inv);
}

// ---------- unfold (bh,L,32) -> (b,256,L) ---------------------------
__global__ __launch_bounds__(256) void unfold_kernel(const float* __restrict__ att,
        float* __restrict__ Fo) {
    __shared__ float tbuf[32][65];
    int bh = blockIdx.y, l0 = blockIdx.x * 64;
    int b = bh >> 3, h = bh & 7;
    int tid = threadIdx.x;
    #pragma unroll
    for (int r = 0; r < 8; r++) {
        int e = r * 256 + tid;
        int l = e >> 5, d = e & 31;
        tbuf[d][l] = att[((size_t)bh * 4096 + l0 + l) * 32 + d];
    }
    __syncthreads();
    #pragma unroll
    for (int r = 0; r < 8; r++) {
        int e = r * 256 + tid;
        int d = e >> 6, l = e & 63;
        Fo[((size_t)b * 256 + h * 32 + d) * LSEQ + l0 + l] = tbuf[d][l];
    }
}

// ---------- final LN + scale + residual (numpy orders) --------------
__global__ __launch_bounds__(64) void lnres_np(const float* __restrict__ x,
        const float* __restrict__ g, const float* __restrict__ bt,
        const float* __restrict__ gs, const float* __restrict__ qsrc,
        float* __restrict__ y) {
    int gid = blockIdx.x * 64 + threadIdx.x;
    int b = gid >> 12, l = gid & 4095;
    const float* xb = x + (size_t)b * CDIM * LSEQ + l;
    float s = 0.f;
    for (int c = 0; c < 256; c++) s = fadd(s, xb[(size_t)c * LSEQ]);
    float mean = __fdiv_rn(s, 256.f);
    float s2 = 0.f;
    for (int c = 0; c < 256; c++) {
        float d = fsub(xb[(size_t)c * LSEQ], mean);
        s2 = fadd(s2, fmul(d, d));
    }
    float var = __fdiv_rn(s2, 256.f);
    float den = fadd(__fsqrt_rn(var), 1e-6f);
    float scale = gs[0];
    const float* qb = qsrc + (size_t)b * CDIM * LSEQ + l;
    float* yb = y + (size_t)b * CDIM * LSEQ + l;
    for (int c = 0; c < 256; c++) {
        float d = fsub(xb[(size_t)c * LSEQ], mean);
        float r = fadd(__fdiv_rn(fmul(g[c], d), den), bt[c]);
        yb[(size_t)c * LSEQ] = fadd(fmul(scale, r), qb[(size_t)c * LSEQ]);
    }
}

// ==================================================================
extern "C" void kernel_launch(void* const* d_in, const int* in_sizes, int n_in,
                              void* d_out, int out_size, void* d_ws, size_t ws_size,
                              hipStream_t stream) {
    const float* qsrc   = (const float*)d_in[0];
    const float* ctx    = (const float*)d_in[1];
    const float* w_q    = (const float*)d_in[2];
    const float* w_kv   = (const float*)d_in[3];
    const float* w_out  = (const float*)d_in[4];
    const float* g_ctx  = (const float*)d_in[5];
    const float* b_ctx  = (const float*)d_in[6];
    const float* g_q    = (const float*)d_in[7];
    const float* b_q    = (const float*)d_in[8];
    const float* g_out  = (const float*)d_in[9];
    const float* b_out  = (const float*)d_in[10];
    const float* gs     = (const float*)d_in[11];

    char* base = (char*)d_ws;
    const size_t MB = 1024 * 1024;
    float* yln   = (float*)base;               // [0,8) LN out; later att
    float* att   = (float*)base;
    float* kvbuf = (float*)(base + 8 * MB);    // [8,24) kv conv; later y32 [8,16)
    float* y32   = (float*)(base + 8 * MB);
    float* qbuf  = (float*)(base + 24 * MB);   // [24,32) q conv; later Fo
    float* Fo    = (float*)(base + 24 * MB);
    float* q_t   = (float*)(base + 32 * MB);   // [32,40)
    float* k_t   = (float*)(base + 40 * MB);   // [40,48)
    float* v_t   = (float*)(base + 48 * MB);   // [48,56)
    char* SM = base + 56 * MB;
    float* xx_q      = (float*)(SM + 0);            // 256 KB
    float* xx_k      = (float*)(SM + 256 * 1024);   // 256 KB
    float* cent      = (float*)(SM + 512 * 1024);   // 32 KB
    float* cc        = (float*)(SM + 576 * 1024);   // 1 KB
    float* sums      = (float*)(SM + 640 * 1024);   // 32 KB
    int*   cnts      = (int*)  (SM + 704 * 1024);   // 1 KB
    int*   asn       = (int*)  (SM + 768 * 1024);   // 256 KB
    int*   hist      = (int*)  (SM + 1024 * 1024);  // 256 KB
    int*   chunkbase = (int*)  (SM + 1280 * 1024);  // 256 KB
    int*   cbase     = (int*)  (SM + 1536 * 1024);  // 1 KB
    int*   perm      = (int*)  (SM + 1600 * 1024);  // 256 KB
    float* kd        = (float*)(SM + 1856 * 1024);  // 256 KB
    float* ksel      = (float*)(SM + 2112 * 1024);  // 512 KB
    float* vsel      = (float*)(SM + 2624 * 1024);  // 512 KB

    // context branch
    ln_np<<<128, 64, 0, stream>>>(ctx, g_ctx, b_ctx, yln);
    conv_np<<<dim3(16, 8, 2), 256, 0, stream>>>(w_kv, 0, yln, kvbuf, 512);
    fold_np<<<256, 256, 0, stream>>>(kvbuf, 512, 0, 1, k_t);
    fold_np<<<256, 256, 0, stream>>>(kvbuf, 512, 256, 0, v_t);
    // query branch
    ln_np<<<128, 64, 0, stream>>>(qsrc, g_q, b_q, yln);
    conv_np<<<dim3(16, 4, 2), 256, 0, stream>>>(w_q, 0, yln, qbuf, 256);
    fold_np<<<256, 256, 0, stream>>>(qbuf, 256, 0, 1, q_t);

    xx_np<<<256, 256, 0, stream>>>(q_t, xx_q);
    copy32<<<32, 256, 0, stream>>>(q_t, cent, 8192);
    cc_np<<<1, 256, 0, stream>>>(cent, cc);

    for (int it = 0; it < 10; it++) {
        assign_hist_np<<<256, 256, 0, stream>>>(q_t, xx_q, cent, cc, asn, hist);
        scan_np<<<1, 256, 0, stream>>>(hist, chunkbase, cbase, cnts);
        scatter_v2<<<256, 256, 0, stream>>>(asn, chunkbase, cbase, perm);
        sumk_v2<<<256, 256, 0, stream>>>(q_t, perm, cbase, cnts, sums);
        update_cc_np<<<32, 256, 0, stream>>>(cent, sums, cnts, cc);
    }

    xx_np<<<256, 256, 0, stream>>>(k_t, xx_k);
    kdist_np<<<256, 256, 0, stream>>>(k_t, xx_k, cent, cc, kd);
    topk_gather<<<16, 512, 0, stream>>>(kd, k_t, v_t, ksel, vsel);
    attn_kernel<<<dim3(16, 16), 256, 0, stream>>>(q_t, ksel, vsel, att);
    unfold_kernel<<<dim3(64, 16), 256, 0, stream>>>(att, Fo);
    conv_np<<<dim3(16, 4, 2), 256, 0, stream>>>(w_out, 0, Fo, y32, 256);
    lnres_np<<<128, 64, 0, stream>>>(y32, g_out, b_out, gs, qsrc, (float*)d_out);
}

// Round 7
// 1240.316 us; speedup vs baseline: 1.9405x; 1.6291x over previous
//
#include <hip/hip_runtime.h>
#include <math.h>

#define CDIM 256
#define LSEQ 4096
#define NBH 16
#define NPTS 65536
#define KC 256

__device__ __forceinline__ float fadd(float a, float b){ return __fadd_rn(a,b); }
__device__ __forceinline__ float fmul(float a, float b){ return __fmul_rn(a,b); }
__device__ __forceinline__ float fsub(float a, float b){ return __fsub_rn(a,b); }

// numpy contiguous n=32 float32 sum, AVX-512 npyv path (verified R5)
__device__ __forceinline__ float sum32_np(const float* e){
    float l[16];
    #pragma unroll
    for (int j = 0; j < 16; j++) l[j] = fadd(e[j], e[j + 16]);
    float t3[8];
    #pragma unroll
    for (int j = 0; j < 8; j++) t3[j] = fadd(l[j], l[j + 8]);
    float t6[4];
    #pragma unroll
    for (int j = 0; j < 4; j++) t6[j] = fadd(t3[j], t3[j + 4]);
    return fadd(fadd(t6[0], t6[2]), fadd(t6[1], t6[3]));
}

// ---------- LayerNorm, numpy semantics (sequential over c) ----------
__global__ __launch_bounds__(64) void ln_np(const float* __restrict__ x,
        const float* __restrict__ g, const float* __restrict__ bt,
        float* __restrict__ y) {
    int gid = blockIdx.x * 64 + threadIdx.x;
    int b = gid >> 12, l = gid & 4095;
    const float* xb = x + (size_t)b * CDIM * LSEQ + l;
    float s = 0.f;
    for (int c = 0; c < 256; c++) s = fadd(s, xb[(size_t)c * LSEQ]);
    float mean = __fdiv_rn(s, 256.f);
    float s2 = 0.f;
    for (int c = 0; c < 256; c++) {
        float d = fsub(xb[(size_t)c * LSEQ], mean);
        s2 = fadd(s2, fmul(d, d));
    }
    float var = __fdiv_rn(s2, 256.f);
    float den = fadd(__fsqrt_rn(var), 1e-6f);
    float* yb = y + (size_t)b * CDIM * LSEQ + l;
    for (int c = 0; c < 256; c++) {
        float d = fsub(xb[(size_t)c * LSEQ], mean);
        yb[(size_t)c * LSEQ] = fadd(__fdiv_rn(fmul(g[c], d), den), bt[c]);
    }
}

// ---------- conv1x1, numpy einsum SOP semantics, o-tile 32 ----------
#define COT 32
__global__ __launch_bounds__(256) void conv_np(const float* __restrict__ W, int wrow0,
        const float* __restrict__ X, float* __restrict__ Y, int nrows) {
    __shared__ float ws[COT * 256];
    int tid = threadIdx.x;
    int l = blockIdx.x * 256 + tid;
    int o0 = blockIdx.y * COT;
    int b = blockIdx.z;
    {
        const float4* wb4 = (const float4*)(W + (size_t)(wrow0 + o0) * CDIM);
        float4* ws4 = (float4*)ws;
        for (int i = tid; i < COT * 64; i += 256) ws4[i] = wb4[i];
    }
    __syncthreads();
    const float* xb = X + (size_t)b * CDIM * LSEQ + l;
    float acc[COT];
    #pragma unroll
    for (int i = 0; i < COT; i++) acc[i] = 0.f;
    const float4* ws4 = (const float4*)ws;
    for (int c = 0; c < 256; c += 4) {
        float x0 = xb[(size_t)(c + 0) * LSEQ];
        float x1 = xb[(size_t)(c + 1) * LSEQ];
        float x2 = xb[(size_t)(c + 2) * LSEQ];
        float x3 = xb[(size_t)(c + 3) * LSEQ];
        #pragma unroll
        for (int oo = 0; oo < COT; oo++) {
            float4 w = ws4[(oo * 256 + c) >> 2];
            acc[oo] = fadd(acc[oo], fmul(w.x, x0));
            acc[oo] = fadd(acc[oo], fmul(w.y, x1));
            acc[oo] = fadd(acc[oo], fmul(w.z, x2));
            acc[oo] = fadd(acc[oo], fmul(w.w, x3));
        }
    }
    for (int oo = 0; oo < COT; oo++)
        Y[((size_t)b * nrows + o0 + oo) * LSEQ + l] = acc[oo];
}

// ---------- fold (+ optional l2norm) --------------------------------
__global__ __launch_bounds__(256) void fold_np(const float* __restrict__ src,
        int srcRows, int row0, int donorm, float* __restrict__ dst) {
    int p = blockIdx.x * 256 + threadIdx.x;
    int bh = p >> 12, l = p & 4095;
    int b = bh >> 3, h = bh & 7;
    const float* sp = src + ((size_t)b * srcRows + row0 + h * 32) * LSEQ + l;
    float x[32];
    #pragma unroll
    for (int t = 0; t < 32; t++) x[t] = sp[(size_t)t * LSEQ];
    float4* dp4 = (float4*)(dst + (size_t)p * 32);
    if (donorm) {
        float ss = 0.f;
        #pragma unroll
        for (int t = 0; t < 32; t++) ss = fadd(ss, fmul(x[t], x[t]));
        float n = __fsqrt_rn(ss);
        float den = fmaxf(n, 1e-12f);
        #pragma unroll
        for (int t = 0; t < 32; t++) x[t] = __fdiv_rn(x[t], den);
    }
    #pragma unroll
    for (int t = 0; t < 8; t++)
        dp4[t] = make_float4(x[4*t], x[4*t+1], x[4*t+2], x[4*t+3]);
}

__global__ void copy32(const float* __restrict__ s, float* __restrict__ d, int n) {
    int i = blockIdx.x * 256 + threadIdx.x;
    if (i < n) d[i] = s[i];
}

// ---------- ||x||^2 per point (AVX-512 tree) ------------------------
__global__ __launch_bounds__(256) void xx_np(const float* __restrict__ pts,
        float* __restrict__ xx) {
    int p = blockIdx.x * 256 + threadIdx.x;
    const float4* x4 = (const float4*)(pts + (size_t)p * 32);
    float x[32];
    #pragma unroll
    for (int t = 0; t < 8; t++) {
        float4 f = x4[t];
        x[4*t] = f.x; x[4*t+1] = f.y; x[4*t+2] = f.z; x[4*t+3] = f.w;
    }
    float e[32];
    #pragma unroll
    for (int t = 0; t < 32; t++) e[t] = fmul(x[t], x[t]);
    xx[p] = sum32_np(e);
}

// ---------- ||c||^2 per centroid (initial) --------------------------
__global__ __launch_bounds__(256) void cc_np(const float* __restrict__ cent,
        float* __restrict__ cc) {
    int j = threadIdx.x;
    const float* c = cent + (size_t)j * 32;
    float e[32];
    #pragma unroll
    for (int t = 0; t < 32; t++) e[t] = fmul(c[t], c[t]);
    cc[j] = sum32_np(e);
}

// ---------- argmin + block-local histogram (LDS-staged) -------------
__global__ __launch_bounds__(256) void assign_hist_np(const float* __restrict__ pts,
        const float* __restrict__ xx, const float* __restrict__ cent,
        const float* __restrict__ cc, int* __restrict__ asn, int* __restrict__ hist) {
    __shared__ float sc[8192];
    __shared__ float scc[256];
    __shared__ int bins[256];
    int tid = threadIdx.x, c = blockIdx.x;
    {
        const float4* c4 = (const float4*)cent;
        float4* s4 = (float4*)sc;
        for (int i = tid; i < 2048; i += 256) s4[i] = c4[i];
    }
    scc[tid] = cc[tid];
    bins[tid] = 0;
    __syncthreads();
    int p = c * 256 + tid;
    float x[32];
    {
        const float4* pp = (const float4*)(pts + (size_t)p * 32);
        #pragma unroll
        for (int t = 0; t < 8; t++) {
            float4 f = pp[t];
            x[4*t] = f.x; x[4*t+1] = f.y; x[4*t+2] = f.z; x[4*t+3] = f.w;
        }
    }
    float xp = xx[p];
    float bd = 3.4e38f; int bj = 0;
    #pragma unroll 2
    for (int j = 0; j < 256; j++) {
        const float4* cj = (const float4*)(sc + j * 32);
        float g = 0.f;
        #pragma unroll
        for (int t = 0; t < 8; t++) {
            float4 w = cj[t];
            g = __builtin_fmaf(x[4*t],   w.x, g);
            g = __builtin_fmaf(x[4*t+1], w.y, g);
            g = __builtin_fmaf(x[4*t+2], w.z, g);
            g = __builtin_fmaf(x[4*t+3], w.w, g);
        }
        float d = fadd(fsub(xp, fmul(2.f, g)), scc[j]);
        if (d < bd) { bd = d; bj = j; }
    }
    asn[p] = bj;
    atomicAdd(&bins[bj], 1);
    __syncthreads();
    hist[c * 256 + tid] = bins[tid];
}

// ---------- parallel scan: per-j prefix over chunks -----------------
__global__ __launch_bounds__(256) void scan_chunks(const int* __restrict__ hist,
        int* __restrict__ chunkbase, int* __restrict__ totals) {
    __shared__ int a[256];
    int j = blockIdx.x, c = threadIdx.x;
    a[c] = hist[c * 256 + j];
    __syncthreads();
    for (int d = 1; d < 256; d <<= 1) {
        int t = a[c];
        int u = (c >= d) ? a[c - d] : 0;
        __syncthreads();
        a[c] = t + u;
        __syncthreads();
    }
    chunkbase[c * 256 + j] = (c == 0) ? 0 : a[c - 1];
    if (c == 255) totals[j] = a[255];
}

__global__ __launch_bounds__(256) void scan_totals(const int* __restrict__ totals,
        int* __restrict__ cbase, int* __restrict__ cnts) {
    __shared__ int a[256];
    int j = threadIdx.x;
    int tj = totals[j];
    a[j] = tj;
    cnts[j] = tj;
    __syncthreads();
    for (int d = 1; d < 256; d <<= 1) {
        int t = a[j];
        int u = (j >= d) ? a[j - d] : 0;
        __syncthreads();
        a[j] = t + u;
        __syncthreads();
    }
    cbase[j] = (j == 0) ? 0 : a[j - 1];
}

// ---------- scatter with parallel stable rank -----------------------
__global__ __launch_bounds__(256) void scatter_v2(const int* __restrict__ asn,
        const int* __restrict__ chunkbase, const int* __restrict__ cbase,
        int* __restrict__ perm) {
    __shared__ int a[256];
    int c = blockIdx.x, tid = threadIdx.x;
    a[tid] = asn[c * 256 + tid];
    __syncthreads();
    int my = a[tid];
    int r = 0;
    for (int i = 0; i < tid; i++) r += (a[i] == my) ? 1 : 0;
    perm[cbase[my] + chunkbase[c * 256 + my] + r] = c * 256 + tid;
}

// ---------- ordered per-cluster sums + update + cc (fused) ----------
#define STILE 128
__global__ __launch_bounds__(256) void sumk_upd(const float* __restrict__ pts,
        const int* __restrict__ perm, const int* __restrict__ cbase,
        const int* __restrict__ cnts, float* __restrict__ cent,
        float* __restrict__ cc) {
    __shared__ float buf[2][STILE][32];
    int j = blockIdx.x, tid = threadIdx.x;
    int base = cbase[j], n = cnts[j];
    int t = tid & 31, r0 = tid >> 5;
    for (int r = r0; r < STILE; r += 8) {
        if (r < n) buf[0][r][t] = pts[(size_t)perm[base + r] * 32 + t];
    }
    __syncthreads();
    float s = 0.f;
    int b = 0;
    for (int i0 = 0; i0 < n; i0 += STILE, b ^= 1) {
        int nx = i0 + STILE;
        if (nx < n) {
            for (int r = r0; r < STILE; r += 8) {
                int g = nx + r;
                if (g < n) buf[b ^ 1][r][t] = pts[(size_t)perm[base + g] * 32 + t];
            }
        }
        if (tid < 32) {
            int m = n - i0; if (m > STILE) m = STILE;
            int i = 0;
            for (; i + 4 <= m; i += 4) {
                s = fadd(s, buf[b][i][tid]);
                s = fadd(s, buf[b][i + 1][tid]);
                s = fadd(s, buf[b][i + 2][tid]);
                s = fadd(s, buf[b][i + 3][tid]);
            }
            for (; i < m; i++) s = fadd(s, buf[b][i][tid]);
        }
        __syncthreads();
    }
    if (tid < 32) {
        float v;
        if (n > 0) {
            v = __fdiv_rn(s, (float)n);
            cent[(size_t)j * 32 + tid] = v;
        } else {
            v = cent[(size_t)j * 32 + tid];
        }
        // exact sum32_np tree via xor butterfly (verified R6)
        float e = fmul(v, v);
        e = fadd(e, __shfl_xor(e, 16));
        e = fadd(e, __shfl_xor(e, 8));
        e = fadd(e, __shfl_xor(e, 4));
        e = fadd(e, __shfl_xor(e, 2));
        e = fadd(e, __shfl_xor(e, 1));
        if (tid == 0) cc[j] = e;
    }
}

// ---------- key assign + L1 dist (LDS-staged) -----------------------
__global__ __launch_bounds__(256) void kdist_np(const float* __restrict__ pts,
        const float* __restrict__ xx, const float* __restrict__ cent,
        const float* __restrict__ cc, float* __restrict__ kd) {
    __shared__ float sc[8192];
    __shared__ float scc[256];
    int tid = threadIdx.x;
    {
        const float4* c4 = (const float4*)cent;
        float4* s4 = (float4*)sc;
        for (int i = tid; i < 2048; i += 256) s4[i] = c4[i];
    }
    scc[tid] = cc[tid];
    __syncthreads();
    int p = blockIdx.x * 256 + tid;
    float x[32];
    {
        const float4* pp = (const float4*)(pts + (size_t)p * 32);
        #pragma unroll
        for (int t = 0; t < 8; t++) {
            float4 f = pp[t];
            x[4*t] = f.x; x[4*t+1] = f.y; x[4*t+2] = f.z; x[4*t+3] = f.w;
        }
    }
    float xp = xx[p];
    float bd = 3.4e38f; int bj = 0;
    #pragma unroll 2
    for (int j = 0; j < 256; j++) {
        const float4* cj = (const float4*)(sc + j * 32);
        float g = 0.f;
        #pragma unroll
        for (int t = 0; t < 8; t++) {
            float4 w = cj[t];
            g = __builtin_fmaf(x[4*t],   w.x, g);
            g = __builtin_fmaf(x[4*t+1], w.y, g);
            g = __builtin_fmaf(x[4*t+2], w.z, g);
            g = __builtin_fmaf(x[4*t+3], w.w, g);
        }
        float d = fadd(fsub(xp, fmul(2.f, g)), scc[j]);
        if (d < bd) { bd = d; bj = j; }
    }
    const float* cb = &sc[bj * 32];
    float e[32];
    #pragma unroll
    for (int t = 0; t < 32; t++) e[t] = fabsf(fsub(cb[t], x[t]));
    kd[p] = sum32_np(e);
}

// ---------- top-256 via radix select (exact set) + gather -----------
// kd >= 0 so IEEE float order == uint order. Set = {v > T} ∪ first-r
// (index asc) of {v == T}: identical to stable desc-sort top-256.
// Output in index-ascending order (value-path only).
__global__ __launch_bounds__(256) void topk_v2(const float* __restrict__ kd,
        const float* __restrict__ k_t, const float* __restrict__ v_t,
        float* __restrict__ ksel, float* __restrict__ vsel) {
    __shared__ unsigned uv[4096];
    __shared__ int hist[256];
    __shared__ unsigned s_prefix;
    __shared__ int s_rem;
    __shared__ int sc1[256];
    __shared__ int out_src[256];
    int bh = blockIdx.x, tid = threadIdx.x;
    for (int i = tid; i < 4096; i += 256) uv[i] = __float_as_uint(kd[bh * 4096 + i]);
    if (tid == 0) { s_prefix = 0u; s_rem = 256; }
    out_src[tid] = 0;
    __syncthreads();
    for (int pass = 0; pass < 4; pass++) {
        int shift = 24 - 8 * pass;
        hist[tid] = 0;
        __syncthreads();
        unsigned pfx = s_prefix;
        for (int i = tid; i < 4096; i += 256) {
            unsigned u = uv[i];
            bool in = (pass == 0) || ((u >> (shift + 8)) == (pfx >> (shift + 8)));
            if (in) atomicAdd(&hist[(u >> shift) & 255], 1);
        }
        __syncthreads();
        if (tid == 0) {
            int rem = s_rem, cum = 0, b;
            for (b = 255; b >= 0; b--) {
                if (cum + hist[b] >= rem) break;
                cum += hist[b];
            }
            s_rem = rem - cum;
            s_prefix = s_prefix | ((unsigned)b << shift);
        }
        __syncthreads();
    }
    unsigned T = s_prefix;
    int r = s_rem;
    int base_i = tid * 16;
    // scan A: eq counts -> global eq rank offsets
    int ec = 0;
    for (int q = 0; q < 16; q++) ec += (uv[base_i + q] == T) ? 1 : 0;
    sc1[tid] = ec;
    __syncthreads();
    for (int d = 1; d < 256; d <<= 1) {
        int t0 = sc1[tid];
        int u0 = (tid >= d) ? sc1[tid - d] : 0;
        __syncthreads();
        sc1[tid] = t0 + u0;
        __syncthreads();
    }
    int erank = (tid == 0) ? 0 : sc1[tid - 1];
    __syncthreads();
    // include predicate + local count
    bool incl[16];
    int ic = 0;
    for (int q = 0; q < 16; q++) {
        unsigned u = uv[base_i + q];
        bool inc;
        if (u > T) inc = true;
        else if (u == T) { inc = (erank < r); erank++; }
        else inc = false;
        incl[q] = inc;
        ic += inc ? 1 : 0;
    }
    sc1[tid] = ic;
    __syncthreads();
    for (int d = 1; d < 256; d <<= 1) {
        int t0 = sc1[tid];
        int u0 = (tid >= d) ? sc1[tid - d] : 0;
        __syncthreads();
        sc1[tid] = t0 + u0;
        __syncthreads();
    }
    int pos = (tid == 0) ? 0 : sc1[tid - 1];
    for (int q = 0; q < 16; q++) {
        if (incl[q]) out_src[pos++] = base_i + q;
    }
    __syncthreads();
    for (int e = tid; e < 256 * 32; e += 256) {
        int jj = e >> 5, t = e & 31;
        int src = out_src[jj];
        ksel[(size_t)bh * 8192 + e] = k_t[((size_t)bh * 4096 + src) * 32 + t];
        vsel[(size_t)bh * 8192 + e] = v_t[((size_t)bh * 4096 + src) * 32 + t];
    }
}

// ---------- attention (online softmax), fp32 value path -------------
__global__ __launch_bounds__(256) void attn_kernel(const float* __restrict__ q_t,
        const float* __restrict__ ksel, const float* __restrict__ vsel,
        float* __restrict__ out) {
    __shared__ float sk[8192];
    __shared__ float sv[8192];
    int bh = blockIdx.y, tid = threadIdx.x;
    {
        const float4* gk = (const float4*)(ksel + (size_t)bh * 8192);
        const float4* gv = (const float4*)(vsel + (size_t)bh * 8192);
        float4* k4s = (float4*)sk; float4* v4s = (float4*)sv;
        for (int i = tid; i < 2048; i += 256) { k4s[i] = gk[i]; v4s[i] = gv[i]; }
    }
    __syncthreads();
    int p = bh * 4096 + blockIdx.x * 256 + tid;
    float q[32];
    const float4* qp = (const float4*)(q_t + (size_t)p * 32);
    #pragma unroll
    for (int t = 0; t < 8; t++) {
        float4 f = qp[t];
        q[4*t] = f.x; q[4*t+1] = f.y; q[4*t+2] = f.z; q[4*t+3] = f.w;
    }
    float o[32];
    #pragma unroll
    for (int t = 0; t < 32; t++) o[t] = 0.f;
    float m = -3.0e38f, lsum = 0.f;
    const float4* k4 = (const float4*)sk;
    const float4* v4 = (const float4*)sv;
    for (int j = 0; j < 256; j++) {
        float s = 0.f;
        #pragma unroll
        for (int t = 0; t < 8; t++) {
            float4 kf = k4[j * 8 + t];
            s += q[4*t]*kf.x + q[4*t+1]*kf.y + q[4*t+2]*kf.z + q[4*t+3]*kf.w;
        }
        float mn = fmaxf(m, s);
        float alpha = expf(m - mn);
        float w = expf(s - mn);
        lsum = lsum * alpha + w;
        #pragma unroll
        for (int t = 0; t < 8; t++) {
            float4 vf = v4[j * 8 + t];
            o[4*t]   = o[4*t]   * alpha + w * vf.x;
            o[4*t+1] = o[4*t+1] * alpha + w * vf.y;
            o[4*t+2] = o[4*t+2] * alpha + w * vf.z;
            o[4*t+3] = o[4*t+3] * alpha + w * vf.w;
        }
        m = mn;
    }
    float inv = 1.f / lsum;
    float4* op = (float4*)(out + (size_t)p * 32);
    #pragma unroll
    for (int t = 0; t < 8; t++)
        op[t] = make_float4(o[4*t]*inv, o[4*t+1]*inv, o[4*t+2]*inv, o[4*t+3]*inv);
}

// ---------- unfold (bh,L,32) -> (b,256,L) ---------------------------
__global__ __launch_bounds__(256) void unfold_kernel(const float* __restrict__ att,
        float* __restrict__ Fo) {
    __shared__ float tbuf[32][65];
    int bh = blockIdx.y, l0 = blockIdx.x * 64;
    int b = bh >> 3, h = bh & 7;
    int tid = threadIdx.x;
    #pragma unroll
    for (int r = 0; r < 8; r++) {
        int e = r * 256 + tid;
        int l = e >> 5, d = e & 31;
        tbuf[d][l] = att[((size_t)bh * 4096 + l0 + l) * 32 + d];
    }
    __syncthreads();
    #pragma unroll
    for (int r = 0; r < 8; r++) {
        int e = r * 256 + tid;
        int d = e >> 6, l = e & 63;
        Fo[((size_t)b * 256 + h * 32 + d) * LSEQ + l0 + l] = tbuf[d][l];
    }
}

// ---------- final LN + scale + residual (numpy orders) --------------
__global__ __launch_bounds__(64) void lnres_np(const float* __restrict__ x,
        const float* __restrict__ g, const float* __restrict__ bt,
        const float* __restrict__ gs, const float* __restrict__ qsrc,
        float* __restrict__ y) {
    int gid = blockIdx.x * 64 + threadIdx.x;
    int b = gid >> 12, l = gid & 4095;
    const float* xb = x + (size_t)b * CDIM * LSEQ + l;
    float s = 0.f;
    for (int c = 0; c < 256; c++) s = fadd(s, xb[(size_t)c * LSEQ]);
    float mean = __fdiv_rn(s, 256.f);
    float s2 = 0.f;
    for (int c = 0; c < 256; c++) {
        float d = fsub(xb[(size_t)c * LSEQ], mean);
        s2 = fadd(s2, fmul(d, d));
    }
    float var = __fdiv_rn(s2, 256.f);
    float den = fadd(__fsqrt_rn(var), 1e-6f);
    float scale = gs[0];
    const float* qb = qsrc + (size_t)b * CDIM * LSEQ + l;
    float* yb = y + (size_t)b * CDIM * LSEQ + l;
    for (int c = 0; c < 256; c++) {
        float d = fsub(xb[(size_t)c * LSEQ], mean);
        float r = fadd(__fdiv_rn(fmul(g[c], d), den), bt[c]);
        yb[(size_t)c * LSEQ] = fadd(fmul(scale, r), qb[(size_t)c * LSEQ]);
    }
}

// ==================================================================
extern "C" void kernel_launch(void* const* d_in, const int* in_sizes, int n_in,
                              void* d_out, int out_size, void* d_ws, size_t ws_size,
                              hipStream_t stream) {
    const float* qsrc   = (const float*)d_in[0];
    const float* ctx    = (const float*)d_in[1];
    const float* w_q    = (const float*)d_in[2];
    const float* w_kv   = (const float*)d_in[3];
    const float* w_out  = (const float*)d_in[4];
    const float* g_ctx  = (const float*)d_in[5];
    const float* b_ctx  = (const float*)d_in[6];
    const float* g_q    = (const float*)d_in[7];
    const float* b_q    = (const float*)d_in[8];
    const float* g_out  = (const float*)d_in[9];
    const float* b_out  = (const float*)d_in[10];
    const float* gs     = (const float*)d_in[11];

    char* base = (char*)d_ws;
    const size_t MB = 1024 * 1024;
    float* yln   = (float*)base;               // [0,8) LN out; later att
    float* att   = (float*)base;
    float* kvbuf = (float*)(base + 8 * MB);    // [8,24) kv conv; later y32 [8,16)
    float* y32   = (float*)(base + 8 * MB);
    float* qbuf  = (float*)(base + 24 * MB);   // [24,32) q conv; later Fo
    float* Fo    = (float*)(base + 24 * MB);
    float* q_t   = (float*)(base + 32 * MB);   // [32,40)
    float* k_t   = (float*)(base + 40 * MB);   // [40,48)
    float* v_t   = (float*)(base + 48 * MB);   // [48,56)
    char* SM = base + 56 * MB;
    float* xx_q      = (float*)(SM + 0);            // 256 KB
    float* xx_k      = (float*)(SM + 256 * 1024);   // 256 KB
    float* cent      = (float*)(SM + 512 * 1024);   // 32 KB
    float* cc        = (float*)(SM + 576 * 1024);   // 1 KB
    int*   totals    = (int*)  (SM + 640 * 1024);   // 1 KB
    int*   cnts      = (int*)  (SM + 704 * 1024);   // 1 KB
    int*   asn       = (int*)  (SM + 768 * 1024);   // 256 KB
    int*   hist      = (int*)  (SM + 1024 * 1024);  // 256 KB
    int*   chunkbase = (int*)  (SM + 1280 * 1024);  // 256 KB
    int*   cbase     = (int*)  (SM + 1536 * 1024);  // 1 KB
    int*   perm      = (int*)  (SM + 1600 * 1024);  // 256 KB
    float* kd        = (float*)(SM + 1856 * 1024);  // 256 KB
    float* ksel      = (float*)(SM + 2112 * 1024);  // 512 KB
    float* vsel      = (float*)(SM + 2624 * 1024);  // 512 KB

    // context branch
    ln_np<<<128, 64, 0, stream>>>(ctx, g_ctx, b_ctx, yln);
    conv_np<<<dim3(16, 16, 2), 256, 0, stream>>>(w_kv, 0, yln, kvbuf, 512);
    fold_np<<<256, 256, 0, stream>>>(kvbuf, 512, 0, 1, k_t);
    fold_np<<<256, 256, 0, stream>>>(kvbuf, 512, 256, 0, v_t);
    // query branch
    ln_np<<<128, 64, 0, stream>>>(qsrc, g_q, b_q, yln);
    conv_np<<<dim3(16, 8, 2), 256, 0, stream>>>(w_q, 0, yln, qbuf, 256);
    fold_np<<<256, 256, 0, stream>>>(qbuf, 256, 0, 1, q_t);

    xx_np<<<256, 256, 0, stream>>>(q_t, xx_q);
    copy32<<<32, 256, 0, stream>>>(q_t, cent, 8192);
    cc_np<<<1, 256, 0, stream>>>(cent, cc);

    for (int it = 0; it < 10; it++) {
        assign_hist_np<<<256, 256, 0, stream>>>(q_t, xx_q, cent, cc, asn, hist);
        scan_chunks<<<256, 256, 0, stream>>>(hist, chunkbase, totals);
        scan_totals<<<1, 256, 0, stream>>>(totals, cbase, cnts);
        scatter_v2<<<256, 256, 0, stream>>>(asn, chunkbase, cbase, perm);
        sumk_upd<<<256, 256, 0, stream>>>(q_t, perm, cbase, cnts, cent, cc);
    }

    xx_np<<<256, 256, 0, stream>>>(k_t, xx_k);
    kdist_np<<<256, 256, 0, stream>>>(k_t, xx_k, cent, cc, kd);
    topk_v2<<<16, 256, 0, stream>>>(kd, k_t, v_t, ksel, vsel);
    attn_kernel<<<dim3(16, 16), 256, 0, stream>>>(q_t, ksel, vsel, att);
    unfold_kernel<<<dim3(64, 16), 256, 0, stream>>>(att, Fo);
    conv_np<<<dim3(16, 8, 2), 256, 0, stream>>>(w_out, 0, Fo, y32, 256);
    lnres_np<<<128, 64, 0, stream>>>(y32, g_out, b_out, gs, qsrc, (float*)d_out);
}